// Round 14
// baseline (998.196 us; speedup 1.0000x reference)
//
#include <hip/hip_runtime.h>
#include <hip/hip_bf16.h>
#include <math.h>

#define NN 100000
#define EE 400000
#define KD 2
#define DD 256
#define ATTD 64
#define LL 3
#define HH1 128
#define HH2 64
#define EPSV 1e-5f
#define SLOPE 0.01f
#define KN (KD * NN)
#define WFP 33554432.0f   // 2^25 fixed-point scale for packed degree sum

typedef short short8 __attribute__((ext_vector_type(8)));
typedef float floatx4 __attribute__((ext_vector_type(4)));
typedef unsigned int u32x4 __attribute__((ext_vector_type(4)));
typedef unsigned short u16;
typedef unsigned int u32;
typedef unsigned long long u64;

__device__ __forceinline__ u16 f2bf(float f) {
    u32 u = __float_as_uint(f);
    return (u16)((u + 0x7fffu + ((u >> 16) & 1u)) >> 16);
}
__device__ __forceinline__ float bf2f(u16 h) {
    return __uint_as_float((u32)h << 16);
}

__device__ __forceinline__ void fma_row8_(float4& a0, float4& a1, uint4 w, float nv) {
    float2 f0 = __bfloat1622float2(*(const __hip_bfloat162*)&w.x);
    float2 f1 = __bfloat1622float2(*(const __hip_bfloat162*)&w.y);
    float2 f2 = __bfloat1622float2(*(const __hip_bfloat162*)&w.z);
    float2 f3 = __bfloat1622float2(*(const __hip_bfloat162*)&w.w);
    a0.x += nv * f0.x; a0.y += nv * f0.y; a0.z += nv * f1.x; a0.w += nv * f1.y;
    a1.x += nv * f2.x; a1.y += nv * f2.y; a1.z += nv * f3.x; a1.w += nv * f3.y;
}

// ---------------- BatchNorm ----------------
__global__ void bn_stats(const float* __restrict__ x, float* __restrict__ sums) {
    int d = threadIdx.x;
    int r0 = blockIdx.x * 125;
    float s = 0.f, sq = 0.f;
    for (int r = r0; r < r0 + 125; ++r) {
        float v = x[(size_t)r * DD + d];
        s += v; sq += v * v;
    }
    atomicAdd(&sums[d], s);
    atomicAdd(&sums[DD + d], sq);
}

// writes h as pre-split bf16 hi/lo planes
__global__ void bn_apply(const float* __restrict__ x, const float* __restrict__ sums,
                         const float* __restrict__ gamma, const float* __restrict__ beta,
                         u16* __restrict__ h_hi, u16* __restrict__ h_lo) {
    size_t i = (size_t)blockIdx.x * blockDim.x + threadIdx.x;
    const float inv_n = 1.f / NN;
    int dq = (int)(i & 63) * 4;
    float4 xv = ((const float4*)x)[i];
    ushort4 hv, lv;
    float* xp = (float*)&xv;
    u16* hp = (u16*)&hv; u16* lp = (u16*)&lv;
#pragma unroll
    for (int j = 0; j < 4; ++j) {
        int d = dq + j;
        float mu = sums[d] * inv_n;
        float var = sums[DD + d] * inv_n - mu * mu;
        float inv = rsqrtf(var + EPSV);
        float v = (xp[j] - mu) * inv * gamma[d] + beta[d];
        u16 hb = f2bf(v);
        hp[j] = hb;
        lp[j] = f2bf(v - bf2f(hb));
    }
    ((ushort4*)h_hi)[i] = hv;
    ((ushort4*)h_lo)[i] = lv;
}

// ---------------- degree + CSR count: ONE packed u64 atomic per edge ----------------
__global__ void deg_count(const int* __restrict__ ei, const float* __restrict__ w,
                          u64* __restrict__ dc) {
    int i = blockIdx.x * blockDim.x + threadIdx.x;
    if (i >= KD * EE) return;
    int k = i / EE, e = i - k * EE;
    int col = ei[(size_t)k * 2 * EE + EE + e];
    u64 wfp = (u64)__float2uint_rn(w[i] * WFP);
    atomicAdd(&dc[k * NN + col], ((u64)1 << 32) | wfp);
}

// unpack: low 32b -> dinv (1/sqrt of fixed-point sum), high 32b -> starts (counts)
__global__ void dinv_pack(const u64* __restrict__ dc, float* __restrict__ dinv,
                          int* __restrict__ starts) {
    int i = blockIdx.x * blockDim.x + threadIdx.x;
    if (i >= KN) return;
    u64 p = dc[i];
    float deg = (float)(u32)p * (1.f / WFP);
    dinv[i] = deg > 0.f ? 1.f / sqrtf(deg) : 0.f;
    starts[i] = (int)(p >> 32);
}

#define SCAN_NB ((KN + 255) / 256)   // 782
__global__ void scan_blocks(int* __restrict__ starts, int* __restrict__ bsums) {
    __shared__ int tmp[256];
    int t = threadIdx.x;
    int idx = blockIdx.x * 256 + t;
    int v = (idx < KN) ? starts[idx] : 0;
    tmp[t] = v;
    __syncthreads();
#pragma unroll
    for (int off = 1; off < 256; off <<= 1) {
        int s = (t >= off) ? tmp[t - off] : 0;
        __syncthreads();
        tmp[t] += s;
        __syncthreads();
    }
    if (idx < KN) starts[idx] = tmp[t] - v;          // exclusive
    if (t == 255) bsums[blockIdx.x] = tmp[255];      // block total
}

__global__ void scan_sums(int* __restrict__ bsums) {
    __shared__ int tmp[1024];
    int t = threadIdx.x;
    int v = (t < SCAN_NB) ? bsums[t] : 0;
    tmp[t] = v;
    __syncthreads();
#pragma unroll
    for (int off = 1; off < 1024; off <<= 1) {
        int s = (t >= off) ? tmp[t - off] : 0;
        __syncthreads();
        tmp[t] += s;
        __syncthreads();
    }
    if (t < SCAN_NB) bsums[t] = tmp[t] - v;          // exclusive
}

__global__ void scan_add(int* __restrict__ starts, const int* __restrict__ bsums) {
    int idx = blockIdx.x * 256 + threadIdx.x;
    if (idx < KN) starts[idx] += bsums[blockIdx.x];
}

__global__ void csr_fill(const int* __restrict__ ei, const float* __restrict__ w,
                         const float* __restrict__ dinv,
                         int* __restrict__ starts, int2* __restrict__ edata) {
    int i = blockIdx.x * blockDim.x + threadIdx.x;
    if (i >= KD * EE) return;
    int k = i / EE, e = i - k * EE;
    const int* eik = ei + (size_t)k * 2 * EE;
    int row = eik[e], col = eik[EE + e];
    float nv = dinv[k * NN + col] * w[i] * dinv[k * NN + row];
    int pos = atomicAdd(&starts[k * NN + col], 1);
    edata[pos] = make_int2(row, __float_as_int(nv));
}

// ---------------- merged weight convert+transpose for ALL weights ----------------
#define GCN_T (LL * DD * DD)                 // 196608
#define ATT_T (LL * KD * DD * ATTD)          // 98304
#define P1_T  (DD * HH1)                     // 32768
#define P2_T  (HH1 * HH2)                    // 8192
#define WC_TOTAL (GCN_T + ATT_T + P1_T + P2_T)
__device__ __forceinline__ void wconv1(const float* __restrict__ W, u16* __restrict__ Wt,
                                       int i, int Kd, int Nc) {
    int kk = i / Nc, n = i - kk * Nc;
    Wt[(size_t)n * Kd + kk] = f2bf(W[i]);
}
__global__ void wconv_all(const float* __restrict__ gcnW, u16* __restrict__ gcnWb,
                          const float* __restrict__ attW, u16* __restrict__ attWb,
                          const float* __restrict__ pW1, u16* __restrict__ pW1b,
                          const float* __restrict__ pW2, u16* __restrict__ pW2b) {
    int gid = blockIdx.x * 256 + threadIdx.x;
    if (gid >= WC_TOTAL) return;
    if (gid < GCN_T) {
        int l = gid >> 16, i = gid & 65535;
        wconv1(gcnW + (size_t)l * DD * DD, gcnWb + (size_t)l * DD * DD, i, DD, DD);
    } else if (gid < GCN_T + ATT_T) {
        int g = gid - GCN_T;
        int lk = g >> 14, i = g & 16383;
        wconv1(attW + (size_t)lk * DD * ATTD, attWb + (size_t)lk * ATTD * DD, i, DD, ATTD);
    } else if (gid < GCN_T + ATT_T + P1_T) {
        wconv1(pW1, pW1b, gid - (GCN_T + ATT_T), DD, HH1);
    } else {
        wconv1(pW2, pW2b, gid - (GCN_T + ATT_T + P1_T), HH1, HH2);
    }
}

// ---------------- fold gcn_b into attention bias ----------------
__global__ void att_bias_fold(const float* __restrict__ attW, const float* __restrict__ attb,
                              const float* __restrict__ gcnb, float* __restrict__ batt) {
    int lk = blockIdx.x;          // 0..5
    int a = threadIdx.x;          // 0..63
    int l = lk >> 1;
    const float* W = attW + (size_t)lk * DD * ATTD;
    const float* gb = gcnb + l * DD;
    float s = attb[lk * ATTD + a];
    for (int d = 0; d < DD; ++d) s += gb[d] * W[d * ATTD + a];
    batt[lk * ATTD + a] = s;
}

#define LDSP 40   // LDS row stride in u16 (32 + 8 pad)

// ---------------- MFMA GEMM, BM=64, 4 waves laid out 1x4 across columns ----------------
template<int BN_, int MODE, bool PRESPLIT, bool BIAS, int ACT>
__global__ __launch_bounds__(256) void gemm_mfma(
        const float* __restrict__ A,
        const u16* __restrict__ Ahi, const u16* __restrict__ Alo,
        const u16* __restrict__ Bt, const float* __restrict__ bias,
        float* __restrict__ Cf, u16* __restrict__ Cb,
        int M, int Kd, int Nc) {
    constexpr int JW = BN_ / 64;           // j-frags per wave (wave covers BN_/4 cols)
    __shared__ u16 AsHi[64 * LDSP];
    __shared__ u16 AsLo[64 * LDSP];
    __shared__ u16 Bs[BN_ * LDSP];

    const int tid = threadIdx.x;
    const int lane = tid & 63, wx = tid >> 6;      // wave id 0..3 across columns
    const int lane15 = lane & 15, quad = lane >> 4;
    const int bm = blockIdx.x * 64;
    const int bn = blockIdx.y * BN_;

    floatx4 acc[4][JW];
#pragma unroll
    for (int i = 0; i < 4; ++i)
#pragma unroll
        for (int j = 0; j < JW; ++j) acc[i][j] = (floatx4){0.f, 0.f, 0.f, 0.f};

    for (int k0 = 0; k0 < Kd; k0 += 32) {
        if constexpr (PRESPLIT) {
            {   // 64 rows x 32 u16 per plane = 256 uint4 each; 1 per thread
                int m = tid >> 2, ko = (tid & 3) << 3;
                uint4 vh = make_uint4(0, 0, 0, 0), vl = make_uint4(0, 0, 0, 0);
                if (bm + m < M) {
                    vh = *(const uint4*)(Ahi + (size_t)(bm + m) * Kd + k0 + ko);
                    vl = *(const uint4*)(Alo + (size_t)(bm + m) * Kd + k0 + ko);
                }
                *(uint4*)(void*)(AsHi + m * LDSP + ko) = vh;
                *(uint4*)(void*)(AsLo + m * LDSP + ko) = vl;
            }
        } else {
#pragma unroll
            for (int t = tid; t < 512; t += 256) {
                int m = t >> 3, k4 = (t & 7) << 2;
                float4 v = make_float4(0.f, 0.f, 0.f, 0.f);
                if (bm + m < M) v = *(const float4*)(A + (size_t)(bm + m) * Kd + k0 + k4);
                u16 h0 = f2bf(v.x), h1 = f2bf(v.y), h2 = f2bf(v.z), h3 = f2bf(v.w);
                *(ushort4*)(void*)(AsHi + m * LDSP + k4) = make_ushort4(h0, h1, h2, h3);
                u16 l0 = f2bf(v.x - bf2f(h0)), l1 = f2bf(v.y - bf2f(h1));
                u16 l2 = f2bf(v.z - bf2f(h2)), l3 = f2bf(v.w - bf2f(h3));
                *(ushort4*)(void*)(AsLo + m * LDSP + k4) = make_ushort4(l0, l1, l2, l3);
            }
        }
#pragma unroll
        for (int t = tid; t < BN_ * 4; t += 256) {
            int n = t >> 2, ko = (t & 3) << 3;
            uint4 w = *(const uint4*)(Bt + (size_t)(bn + n) * Kd + k0 + ko);
            *(uint4*)(void*)(Bs + n * LDSP + ko) = w;
        }
        __syncthreads();

        const u16* pA  = AsHi + lane15 * LDSP + quad * 8;
        const u16* pAl = AsLo + lane15 * LDSP + quad * 8;
        const u16* pB  = Bs + (wx * (BN_ / 4) + lane15) * LDSP + quad * 8;
        short8 b[JW];
#pragma unroll
        for (int j = 0; j < JW; ++j) b[j] = *(const short8*)(pB + j * 16 * LDSP);
#pragma unroll
        for (int i = 0; i < 4; ++i) {
            short8 a = *(const short8*)(pA + i * 16 * LDSP);
#pragma unroll
            for (int j = 0; j < JW; ++j)
                acc[i][j] = __builtin_amdgcn_mfma_f32_16x16x32_bf16(a, b[j], acc[i][j], 0, 0, 0);
        }
#pragma unroll
        for (int i = 0; i < 4; ++i) {
            short8 a = *(const short8*)(pAl + i * 16 * LDSP);
#pragma unroll
            for (int j = 0; j < JW; ++j)
                acc[i][j] = __builtin_amdgcn_mfma_f32_16x16x32_bf16(a, b[j], acc[i][j], 0, 0, 0);
        }
        __syncthreads();
    }

#pragma unroll
    for (int i = 0; i < 4; ++i) {
#pragma unroll
        for (int r = 0; r < 4; ++r) {
            int row = bm + i * 16 + quad * 4 + r;
            if (row >= M) continue;
#pragma unroll
            for (int j = 0; j < JW; ++j) {
                int col = bn + wx * (BN_ / 4) + j * 16 + lane15;
                float v = acc[i][j][r];
                if constexpr (BIAS) v += bias[col];
                if constexpr (ACT == 1) v = v > 0.f ? v : SLOPE * v;
                if constexpr (MODE == 0) Cf[(size_t)row * Nc + col] = v;
                else                     Cb[(size_t)row * Nc + col] = f2bf(v);
            }
        }
    }
}

// ---------------- FUSED gather + attention v4: 1024-thread blocks ----------------
// Rounds 10-12: occupancy pinned at 29-31% and dur at 147-149 us across LDS
// 44.5/34.3/17.4 KB -> residency is capped per-BLOCK (~2.5 blocks/CU), not by
// LDS/VGPR. Lever: more waves per block. 1024 threads x 2 blocks/CU = 32
// waves/CU (3x today's 10). BMF=64 rows, 4 rows per half-wave, 2-node
// interleave. LDS 68.6 KB -> exactly 2 blocks/CU.
// NN % 64 != 0 -> starts-index clamp per k + phase-4 row guard.
#define BMF 64
#define ALDS 264   // full-row stride in u16 (16B-aligned rows)

__global__ __launch_bounds__(1024) void att_fused(
        const int* __restrict__ starts, const int2* __restrict__ edata,
        const u16* __restrict__ xw, const u16* __restrict__ Bt,
        const float* __restrict__ batt, const float* __restrict__ qv,
        const float* __restrict__ gcnb,
        u16* __restrict__ h_hi, u16* __restrict__ h_lo) {
    __shared__ u16 As[KD * BMF * ALDS];          // 67584 B
    __shared__ float simbuf[KD][2][BMF];         // 1024 B

    const int tid = threadIdx.x;
    const int lane = tid & 63, waveid = tid >> 6;        // wave 0..15
    const int l32 = tid & 31;
    const int hid = tid >> 5;                            // half-wave 0..31
    const int base = lane & 32;                          // shfl base of own half
    const int bm = blockIdx.x * BMF;

    // ---- phase 1: gather 128 node-rows (64 x 2k) into As ----
    {
        const int kk = hid >> 4;                 // halves 0-15: k=0, 16-31: k=1
        const int r0 = (hid & 15) * 4;           // 4 rows per half
        const int lim = kk * NN + NN;            // clamp for tail block
        const int widx0 = kk * NN + bm + r0;
        int sv = 0;
        if (l32 < 5) {
            int idx = widx0 - 1 + l32;
            if (idx > lim - 1) idx = lim - 1;    // rows >= NN -> empty windows
            sv = idx >= 0 ? starts[idx] : 0;     // starts[i] = end_i (post csr_fill)
        }
        int2 ed[4];
#pragma unroll
        for (int g = 0; g < 4; ++g) {
            int b = __shfl(sv, base + g), e = __shfl(sv, base + g + 1);
            ed[g] = (l32 < e - b) ? edata[b + l32] : make_int2(0, 0);
        }
#pragma unroll
        for (int g = 0; g < 4; g += 2) {
            int bA = __shfl(sv, base + g),     eA = __shfl(sv, base + g + 1);
            int eB = __shfl(sv, base + g + 2);
            int bB = eA;                          // CSR windows are adjacent
            int dA = eA - bA, dB = eB - bB;
            int mA = dA > 32 ? 32 : dA, mB = dB > 32 ? 32 : dB;
            float4 xa0 = make_float4(0.f,0.f,0.f,0.f), xa1 = make_float4(0.f,0.f,0.f,0.f);
            float4 xb0 = make_float4(0.f,0.f,0.f,0.f), xb1 = make_float4(0.f,0.f,0.f,0.f);
            int j = 0;
            for (; j + 4 <= mA && j + 4 <= mB; j += 4) {
                int ra0 = __shfl(ed[g].x, base + j),     ra1 = __shfl(ed[g].x, base + j + 1);
                int ra2 = __shfl(ed[g].x, base + j + 2), ra3 = __shfl(ed[g].x, base + j + 3);
                int rb0 = __shfl(ed[g+1].x, base + j),     rb1 = __shfl(ed[g+1].x, base + j + 1);
                int rb2 = __shfl(ed[g+1].x, base + j + 2), rb3 = __shfl(ed[g+1].x, base + j + 3);
                float na0 = __int_as_float(__shfl(ed[g].y, base + j));
                float na1 = __int_as_float(__shfl(ed[g].y, base + j + 1));
                float na2 = __int_as_float(__shfl(ed[g].y, base + j + 2));
                float na3 = __int_as_float(__shfl(ed[g].y, base + j + 3));
                float nb0 = __int_as_float(__shfl(ed[g+1].y, base + j));
                float nb1 = __int_as_float(__shfl(ed[g+1].y, base + j + 1));
                float nb2 = __int_as_float(__shfl(ed[g+1].y, base + j + 2));
                float nb3 = __int_as_float(__shfl(ed[g+1].y, base + j + 3));
                uint4 wa0 = *(const uint4*)(xw + (size_t)ra0 * DD + l32 * 8);
                uint4 wa1 = *(const uint4*)(xw + (size_t)ra1 * DD + l32 * 8);
                uint4 wa2 = *(const uint4*)(xw + (size_t)ra2 * DD + l32 * 8);
                uint4 wa3 = *(const uint4*)(xw + (size_t)ra3 * DD + l32 * 8);
                uint4 wb0 = *(const uint4*)(xw + (size_t)rb0 * DD + l32 * 8);
                uint4 wb1 = *(const uint4*)(xw + (size_t)rb1 * DD + l32 * 8);
                uint4 wb2 = *(const uint4*)(xw + (size_t)rb2 * DD + l32 * 8);
                uint4 wb3 = *(const uint4*)(xw + (size_t)rb3 * DD + l32 * 8);
                fma_row8_(xa0, xa1, wa0, na0);
                fma_row8_(xa0, xa1, wa1, na1);
                fma_row8_(xa0, xa1, wa2, na2);
                fma_row8_(xa0, xa1, wa3, na3);
                fma_row8_(xb0, xb1, wb0, nb0);
                fma_row8_(xb0, xb1, wb1, nb1);
                fma_row8_(xb0, xb1, wb2, nb2);
                fma_row8_(xb0, xb1, wb3, nb3);
            }
            int jb = j;
            for (; j + 4 <= mA; j += 4) {
                int ra0 = __shfl(ed[g].x, base + j),     ra1 = __shfl(ed[g].x, base + j + 1);
                int ra2 = __shfl(ed[g].x, base + j + 2), ra3 = __shfl(ed[g].x, base + j + 3);
                float na0 = __int_as_float(__shfl(ed[g].y, base + j));
                float na1 = __int_as_float(__shfl(ed[g].y, base + j + 1));
                float na2 = __int_as_float(__shfl(ed[g].y, base + j + 2));
                float na3 = __int_as_float(__shfl(ed[g].y, base + j + 3));
                uint4 wa0 = *(const uint4*)(xw + (size_t)ra0 * DD + l32 * 8);
                uint4 wa1 = *(const uint4*)(xw + (size_t)ra1 * DD + l32 * 8);
                uint4 wa2 = *(const uint4*)(xw + (size_t)ra2 * DD + l32 * 8);
                uint4 wa3 = *(const uint4*)(xw + (size_t)ra3 * DD + l32 * 8);
                fma_row8_(xa0, xa1, wa0, na0);
                fma_row8_(xa0, xa1, wa1, na1);
                fma_row8_(xa0, xa1, wa2, na2);
                fma_row8_(xa0, xa1, wa3, na3);
            }
            for (; j < mA; ++j) {
                int r = __shfl(ed[g].x, base + j);
                float nv = __int_as_float(__shfl(ed[g].y, base + j));
                uint4 w = *(const uint4*)(xw + (size_t)r * DD + l32 * 8);
                fma_row8_(xa0, xa1, w, nv);
            }
            for (; jb + 4 <= mB; jb += 4) {
                int rb0 = __shfl(ed[g+1].x, base + jb),     rb1 = __shfl(ed[g+1].x, base + jb + 1);
                int rb2 = __shfl(ed[g+1].x, base + jb + 2), rb3 = __shfl(ed[g+1].x, base + jb + 3);
                float nb0 = __int_as_float(__shfl(ed[g+1].y, base + jb));
                float nb1 = __int_as_float(__shfl(ed[g+1].y, base + jb + 1));
                float nb2 = __int_as_float(__shfl(ed[g+1].y, base + jb + 2));
                float nb3 = __int_as_float(__shfl(ed[g+1].y, base + jb + 3));
                uint4 wb0 = *(const uint4*)(xw + (size_t)rb0 * DD + l32 * 8);
                uint4 wb1 = *(const uint4*)(xw + (size_t)rb1 * DD + l32 * 8);
                uint4 wb2 = *(const uint4*)(xw + (size_t)rb2 * DD + l32 * 8);
                uint4 wb3 = *(const uint4*)(xw + (size_t)rb3 * DD + l32 * 8);
                fma_row8_(xb0, xb1, wb0, nb0);
                fma_row8_(xb0, xb1, wb1, nb1);
                fma_row8_(xb0, xb1, wb2, nb2);
                fma_row8_(xb0, xb1, wb3, nb3);
            }
            for (; jb < mB; ++jb) {
                int r = __shfl(ed[g+1].x, base + jb);
                float nv = __int_as_float(__shfl(ed[g+1].y, base + jb));
                uint4 w = *(const uint4*)(xw + (size_t)r * DD + l32 * 8);
                fma_row8_(xb0, xb1, w, nv);
            }
            for (int e2 = bA + 32; e2 < eA; ++e2) {      // rare: degA > 32
                int2 ee = edata[e2];
                float nv = __int_as_float(ee.y);
                uint4 w = *(const uint4*)(xw + (size_t)ee.x * DD + l32 * 8);
                fma_row8_(xa0, xa1, w, nv);
            }
            for (int e2 = bB + 32; e2 < eB; ++e2) {      // rare: degB > 32
                int2 ee = edata[e2];
                float nv = __int_as_float(ee.y);
                uint4 w = *(const uint4*)(xw + (size_t)ee.x * DD + l32 * 8);
                fma_row8_(xb0, xb1, w, nv);
            }
            u32x4 st;
            st.x = (u32)f2bf(xa0.x) | ((u32)f2bf(xa0.y) << 16);
            st.y = (u32)f2bf(xa0.z) | ((u32)f2bf(xa0.w) << 16);
            st.z = (u32)f2bf(xa1.x) | ((u32)f2bf(xa1.y) << 16);
            st.w = (u32)f2bf(xa1.z) | ((u32)f2bf(xa1.w) << 16);
            *(u32x4*)(void*)(As + (kk * BMF + r0 + g) * ALDS + l32 * 8) = st;
            st.x = (u32)f2bf(xb0.x) | ((u32)f2bf(xb0.y) << 16);
            st.y = (u32)f2bf(xb0.z) | ((u32)f2bf(xb0.w) << 16);
            st.z = (u32)f2bf(xb1.x) | ((u32)f2bf(xb1.y) << 16);
            st.w = (u32)f2bf(xb1.z) | ((u32)f2bf(xb1.w) << 16);
            *(u32x4*)(void*)(As + (kk * BMF + r0 + g + 1) * ALDS + l32 * 8) = st;
        }
    }
    __syncthreads();

    // ---- phase 2: MFMA — 16 waves = 2k x 2ch x 4 row-stripes; B from global (L2-hot) ----
    const int kw = waveid >> 3;                  // k
    const int ch = (waveid >> 2) & 1;            // column half
    const int stripe = waveid & 3;               // row-stripe of 16
    const int lane15 = lane & 15, quad = lane >> 4;
    floatx4 acc[2];
    acc[0] = (floatx4){0.f, 0.f, 0.f, 0.f};
    acc[1] = (floatx4){0.f, 0.f, 0.f, 0.f};

    const u16* pB0 = Bt + (size_t)kw * ATTD * DD + (size_t)(ch * 32 + lane15) * DD + quad * 8;
    const u16* pB1 = pB0 + 16 * DD;
#pragma unroll
    for (int k0 = 0; k0 < DD; k0 += 32) {
        short8 b0 = *(const short8*)(pB0 + k0);
        short8 b1 = *(const short8*)(pB1 + k0);
        short8 a = *(const short8*)(As + (kw * BMF + stripe * 16 + lane15) * ALDS + k0 + quad * 8);
        acc[0] = __builtin_amdgcn_mfma_f32_16x16x32_bf16(a, b0, acc[0], 0, 0, 0);
        acc[1] = __builtin_amdgcn_mfma_f32_16x16x32_bf16(a, b1, acc[1], 0, 0, 0);
    }

    // ---- phase 3: sim (tanh + q dot, 4-lane-group reduce) ----
#pragma unroll
    for (int r = 0; r < 4; ++r) {
        float p = 0.f;
#pragma unroll
        for (int j = 0; j < 2; ++j) {
            int col = ch * 32 + j * 16 + lane15;
            float v = acc[j][r] + batt[kw * ATTD + col];
            float ex = __expf(2.f * v);
            float th = 1.f - 2.f / (ex + 1.f);     // tanh, inf-safe
            p += th * qv[kw * ATTD + col];
        }
        p += __shfl_xor(p, 1, 64);
        p += __shfl_xor(p, 2, 64);
        p += __shfl_xor(p, 4, 64);
        p += __shfl_xor(p, 8, 64);
        if (lane15 == 0) simbuf[kw][ch][stripe * 16 + quad * 4 + r] = p;
    }
    __syncthreads();

    // ---- phase 4: combine (softmax over k, relu, split) — xs from LDS ----
#pragma unroll
    for (int it = 0; it < 2; ++it) {
        int item = tid + it * 1024;
        int row = item >> 5, c8 = item & 31;
        int grow = bm + row;
        if (grow >= NN) continue;
        float s0 = simbuf[0][0][row] + simbuf[0][1][row];
        float s1 = simbuf[1][0][row] + simbuf[1][1][row];
        float m = fmaxf(s0, s1);
        float e0 = __expf(s0 - m), e1 = __expf(s1 - m);
        float inv = 1.f / (e0 + e1);
        float a0 = e0 * inv, a1 = e1 * inv;
        uint4 x0 = *(const uint4*)(As + row * ALDS + c8 * 8);
        uint4 x1 = *(const uint4*)(As + (BMF + row) * ALDS + c8 * 8);
        const float* bp = gcnb + c8 * 8;
        uint4 hiw, low;
        u16* hp = (u16*)&hiw; u16* lp = (u16*)&low;
        const u32* xp0 = (const u32*)&x0; const u32* xp1 = (const u32*)&x1;
#pragma unroll
        for (int j = 0; j < 4; ++j) {
            float2 f0 = __bfloat1622float2(*(const __hip_bfloat162*)&xp0[j]);
            float2 f1 = __bfloat1622float2(*(const __hip_bfloat162*)&xp1[j]);
            float ra = fmaxf(0.f, a0 * f0.x + a1 * f1.x + bp[2 * j]);
            float rb = fmaxf(0.f, a0 * f0.y + a1 * f1.y + bp[2 * j + 1]);
            u16 ha = f2bf(ra), hb = f2bf(rb);
            hp[2 * j] = ha; hp[2 * j + 1] = hb;
            lp[2 * j] = f2bf(ra - bf2f(ha));
            lp[2 * j + 1] = f2bf(rb - bf2f(hb));
        }
        *(uint4*)(h_hi + (size_t)grow * DD + c8 * 8) = hiw;
        *(uint4*)(h_lo + (size_t)grow * DD + c8 * 8) = low;
    }
}

extern "C" void kernel_launch(void* const* d_in, const int* in_sizes, int n_in,
                              void* d_out, int out_size, void* d_ws, size_t ws_size,
                              hipStream_t stream) {
    const float* x     = (const float*)d_in[0];
    const int*   ei    = (const int*)d_in[1];
    const float* ew    = (const float*)d_in[2];
    const float* gamma = (const float*)d_in[3];
    const float* beta  = (const float*)d_in[4];
    const float* gcn_W = (const float*)d_in[5];
    const float* gcn_b = (const float*)d_in[6];
    const float* att_W = (const float*)d_in[7];
    const float* att_b = (const float*)d_in[8];
    const float* att_q = (const float*)d_in[9];
    const float* pW1   = (const float*)d_in[10];
    const float* pb1   = (const float*)d_in[11];
    const float* pW2   = (const float*)d_in[12];
    const float* pb2   = (const float*)d_in[13];
    float* out = (float*)d_out;

    char* wsb = (char*)d_ws;
    size_t off = 0;
    auto alloc = [&](size_t bytes) -> void* {
        void* p = wsb + off;
        off += (bytes + 255) & ~(size_t)255;
        return p;
    };
    u16*   h_hi  = (u16*)alloc((size_t)NN * DD * 2);          // 51.2 MB
    u16*   h_lo  = (u16*)alloc((size_t)NN * DD * 2);          // 51.2 MB
    u16*   xw    = (u16*)alloc((size_t)NN * DD * 2);          // 51.2 MB
    float* p1tmp = (float*)xw;                                // N*H1*4, exact reuse
    float* dinv  = (float*)alloc((size_t)KN * 4);
    int*   starts= (int*)alloc(((size_t)KN + 1) * 4);
    u64*   dc    = (u64*)alloc((size_t)KN * 8);               // packed deg+count
    int2*  edata = (int2*)alloc((size_t)KD * EE * 8);         // 6.4 MB
    float* bnsums= (float*)alloc(2 * DD * 4);
    u16*   gcnWb = (u16*)alloc((size_t)LL * DD * DD * 2);
    u16*   attWb = (u16*)alloc((size_t)LL * KD * ATTD * DD * 2);
    u16*   pW1b  = (u16*)alloc((size_t)HH1 * DD * 2);
    u16*   pW2b  = (u16*)alloc((size_t)HH2 * HH1 * 2);
    float* batt  = (float*)alloc((size_t)LL * KD * ATTD * 4);
    int*   bsums = (int*)alloc((size_t)SCAN_NB * 4);

    // ---- setup: all weight converts in ONE kernel + att bias fold ----
    wconv_all<<<(WC_TOTAL + 255) / 256, 256, 0, stream>>>(
        gcn_W, gcnWb, att_W, attWb, pW1, pW1b, pW2, pW2b);
    att_bias_fold<<<LL * KD, ATTD, 0, stream>>>(att_W, att_b, gcn_b, batt);

    // ---- BatchNorm -> h (pre-split) ----
    hipMemsetAsync(bnsums, 0, 2 * DD * 4, stream);
    bn_stats<<<800, 256, 0, stream>>>(x, bnsums);
    bn_apply<<<25000, 256, 0, stream>>>(x, bnsums, gamma, beta, h_hi, h_lo);

    // ---- degree / CSR (layer-invariant); single packed-atomic pass ----
    hipMemsetAsync(dc, 0, (size_t)KN * 8, stream);
    deg_count<<<(KD * EE + 255) / 256, 256, 0, stream>>>(ei, ew, dc);
    dinv_pack<<<(KN + 255) / 256, 256, 0, stream>>>(dc, dinv, starts);
    scan_blocks<<<SCAN_NB, 256, 0, stream>>>(starts, bsums);
    scan_sums<<<1, 1024, 0, stream>>>(bsums);
    scan_add<<<SCAN_NB, 256, 0, stream>>>(starts, bsums);
    csr_fill<<<(KD * EE + 255) / 256, 256, 0, stream>>>(ei, ew, dinv, starts, edata);

    const int MB64 = (NN + 63) / 64;     // 1563
    const int MBF  = (NN + BMF - 1) / BMF;  // 1563 (tail block: 32 rows)
    for (int l = 0; l < LL; ++l) {
        // xw(bf16) = h @ gcn_W[l] — BM=64 x BN=256, copy-only staging
        gemm_mfma<256, 1, true, false, 0><<<dim3(MB64, 1), 256, 0, stream>>>(
            nullptr, h_hi, h_lo, gcnWb + (size_t)l * DD * DD, nullptr,
            nullptr, xw, NN, DD, DD);
        att_fused<<<MBF, 1024, 0, stream>>>(
            starts, edata, xw, attWb + (size_t)l * KD * ATTD * DD,
            batt + (size_t)l * KD * ATTD, att_q + (size_t)l * KD * ATTD,
            gcn_b + l * DD, h_hi, h_lo);
    }

    // ---- projection head ----
    gemm_mfma<128, 0, true, true, 1><<<dim3(MB64, 1), 256, 0, stream>>>(
        nullptr, h_hi, h_lo, pW1b, pb1, p1tmp, nullptr, NN, DD, HH1);
    gemm_mfma<64, 0, false, true, 1><<<dim3(MB64, 1), 256, 0, stream>>>(
        p1tmp, nullptr, nullptr, pW2b, pb2, out, nullptr, NN, HH1, HH2);
}

// Round 15
// 844.694 us; speedup vs baseline: 1.1817x; 1.1817x over previous
//
#include <hip/hip_runtime.h>
#include <hip/hip_bf16.h>
#include <math.h>

#define NN 100000
#define EE 400000
#define KD 2
#define DD 256
#define ATTD 64
#define LL 3
#define HH1 128
#define HH2 64
#define EPSV 1e-5f
#define SLOPE 0.01f
#define KN (KD * NN)
#define WFP 33554432.0f   // 2^25 fixed-point scale for packed degree sum

typedef short short8 __attribute__((ext_vector_type(8)));
typedef float floatx4 __attribute__((ext_vector_type(4)));
typedef unsigned int u32x4 __attribute__((ext_vector_type(4)));
typedef unsigned short u16;
typedef unsigned int u32;
typedef unsigned long long u64;

__device__ __forceinline__ u16 f2bf(float f) {
    u32 u = __float_as_uint(f);
    return (u16)((u + 0x7fffu + ((u >> 16) & 1u)) >> 16);
}
__device__ __forceinline__ float bf2f(u16 h) {
    return __uint_as_float((u32)h << 16);
}

__device__ __forceinline__ void fma_row8_(float4& a0, float4& a1, uint4 w, float nv) {
    float2 f0 = __bfloat1622float2(*(const __hip_bfloat162*)&w.x);
    float2 f1 = __bfloat1622float2(*(const __hip_bfloat162*)&w.y);
    float2 f2 = __bfloat1622float2(*(const __hip_bfloat162*)&w.z);
    float2 f3 = __bfloat1622float2(*(const __hip_bfloat162*)&w.w);
    a0.x += nv * f0.x; a0.y += nv * f0.y; a0.z += nv * f1.x; a0.w += nv * f1.y;
    a1.x += nv * f2.x; a1.y += nv * f2.y; a1.z += nv * f3.x; a1.w += nv * f3.y;
}

// ---------------- BatchNorm ----------------
__global__ void bn_stats(const float* __restrict__ x, float* __restrict__ sums) {
    int d = threadIdx.x;
    int r0 = blockIdx.x * 125;
    float s = 0.f, sq = 0.f;
    for (int r = r0; r < r0 + 125; ++r) {
        float v = x[(size_t)r * DD + d];
        s += v; sq += v * v;
    }
    atomicAdd(&sums[d], s);
    atomicAdd(&sums[DD + d], sq);
}

// writes h as pre-split bf16 hi/lo planes
__global__ void bn_apply(const float* __restrict__ x, const float* __restrict__ sums,
                         const float* __restrict__ gamma, const float* __restrict__ beta,
                         u16* __restrict__ h_hi, u16* __restrict__ h_lo) {
    size_t i = (size_t)blockIdx.x * blockDim.x + threadIdx.x;
    const float inv_n = 1.f / NN;
    int dq = (int)(i & 63) * 4;
    float4 xv = ((const float4*)x)[i];
    ushort4 hv, lv;
    float* xp = (float*)&xv;
    u16* hp = (u16*)&hv; u16* lp = (u16*)&lv;
#pragma unroll
    for (int j = 0; j < 4; ++j) {
        int d = dq + j;
        float mu = sums[d] * inv_n;
        float var = sums[DD + d] * inv_n - mu * mu;
        float inv = rsqrtf(var + EPSV);
        float v = (xp[j] - mu) * inv * gamma[d] + beta[d];
        u16 hb = f2bf(v);
        hp[j] = hb;
        lp[j] = f2bf(v - bf2f(hb));
    }
    ((ushort4*)h_hi)[i] = hv;
    ((ushort4*)h_lo)[i] = lv;
}

// ---------------- degree + CSR count: ONE packed u64 atomic per edge ----------------
__global__ void deg_count(const int* __restrict__ ei, const float* __restrict__ w,
                          u64* __restrict__ dc) {
    int i = blockIdx.x * blockDim.x + threadIdx.x;
    if (i >= KD * EE) return;
    int k = i / EE, e = i - k * EE;
    int col = ei[(size_t)k * 2 * EE + EE + e];
    u64 wfp = (u64)__float2uint_rn(w[i] * WFP);
    atomicAdd(&dc[k * NN + col], ((u64)1 << 32) | wfp);
}

// unpack: low 32b -> dinv (1/sqrt of fixed-point sum), high 32b -> starts (counts)
__global__ void dinv_pack(const u64* __restrict__ dc, float* __restrict__ dinv,
                          int* __restrict__ starts) {
    int i = blockIdx.x * blockDim.x + threadIdx.x;
    if (i >= KN) return;
    u64 p = dc[i];
    float deg = (float)(u32)p * (1.f / WFP);
    dinv[i] = deg > 0.f ? 1.f / sqrtf(deg) : 0.f;
    starts[i] = (int)(p >> 32);
}

#define SCAN_NB ((KN + 255) / 256)   // 782
__global__ void scan_blocks(int* __restrict__ starts, int* __restrict__ bsums) {
    __shared__ int tmp[256];
    int t = threadIdx.x;
    int idx = blockIdx.x * 256 + t;
    int v = (idx < KN) ? starts[idx] : 0;
    tmp[t] = v;
    __syncthreads();
#pragma unroll
    for (int off = 1; off < 256; off <<= 1) {
        int s = (t >= off) ? tmp[t - off] : 0;
        __syncthreads();
        tmp[t] += s;
        __syncthreads();
    }
    if (idx < KN) starts[idx] = tmp[t] - v;          // exclusive
    if (t == 255) bsums[blockIdx.x] = tmp[255];      // block total
}

__global__ void scan_sums(int* __restrict__ bsums) {
    __shared__ int tmp[1024];
    int t = threadIdx.x;
    int v = (t < SCAN_NB) ? bsums[t] : 0;
    tmp[t] = v;
    __syncthreads();
#pragma unroll
    for (int off = 1; off < 1024; off <<= 1) {
        int s = (t >= off) ? tmp[t - off] : 0;
        __syncthreads();
        tmp[t] += s;
        __syncthreads();
    }
    if (t < SCAN_NB) bsums[t] = tmp[t] - v;          // exclusive
}

__global__ void scan_add(int* __restrict__ starts, const int* __restrict__ bsums) {
    int idx = blockIdx.x * 256 + threadIdx.x;
    if (idx < KN) starts[idx] += bsums[blockIdx.x];
}

__global__ void csr_fill(const int* __restrict__ ei, const float* __restrict__ w,
                         const float* __restrict__ dinv,
                         int* __restrict__ starts, int2* __restrict__ edata) {
    int i = blockIdx.x * blockDim.x + threadIdx.x;
    if (i >= KD * EE) return;
    int k = i / EE, e = i - k * EE;
    const int* eik = ei + (size_t)k * 2 * EE;
    int row = eik[e], col = eik[EE + e];
    float nv = dinv[k * NN + col] * w[i] * dinv[k * NN + row];
    int pos = atomicAdd(&starts[k * NN + col], 1);
    edata[pos] = make_int2(row, __float_as_int(nv));
}

// ---------------- merged weight convert+transpose for ALL weights ----------------
#define GCN_T (LL * DD * DD)                 // 196608
#define ATT_T (LL * KD * DD * ATTD)          // 98304
#define P1_T  (DD * HH1)                     // 32768
#define P2_T  (HH1 * HH2)                    // 8192
#define WC_TOTAL (GCN_T + ATT_T + P1_T + P2_T)
__device__ __forceinline__ void wconv1(const float* __restrict__ W, u16* __restrict__ Wt,
                                       int i, int Kd, int Nc) {
    int kk = i / Nc, n = i - kk * Nc;
    Wt[(size_t)n * Kd + kk] = f2bf(W[i]);
}
__global__ void wconv_all(const float* __restrict__ gcnW, u16* __restrict__ gcnWb,
                          const float* __restrict__ attW, u16* __restrict__ attWb,
                          const float* __restrict__ pW1, u16* __restrict__ pW1b,
                          const float* __restrict__ pW2, u16* __restrict__ pW2b) {
    int gid = blockIdx.x * 256 + threadIdx.x;
    if (gid >= WC_TOTAL) return;
    if (gid < GCN_T) {
        int l = gid >> 16, i = gid & 65535;
        wconv1(gcnW + (size_t)l * DD * DD, gcnWb + (size_t)l * DD * DD, i, DD, DD);
    } else if (gid < GCN_T + ATT_T) {
        int g = gid - GCN_T;
        int lk = g >> 14, i = g & 16383;
        wconv1(attW + (size_t)lk * DD * ATTD, attWb + (size_t)lk * ATTD * DD, i, DD, ATTD);
    } else if (gid < GCN_T + ATT_T + P1_T) {
        wconv1(pW1, pW1b, gid - (GCN_T + ATT_T), DD, HH1);
    } else {
        wconv1(pW2, pW2b, gid - (GCN_T + ATT_T + P1_T), HH1, HH2);
    }
}

// ---------------- fold gcn_b into attention bias ----------------
__global__ void att_bias_fold(const float* __restrict__ attW, const float* __restrict__ attb,
                              const float* __restrict__ gcnb, float* __restrict__ batt) {
    int lk = blockIdx.x;          // 0..5
    int a = threadIdx.x;          // 0..63
    int l = lk >> 1;
    const float* W = attW + (size_t)lk * DD * ATTD;
    const float* gb = gcnb + l * DD;
    float s = attb[lk * ATTD + a];
    for (int d = 0; d < DD; ++d) s += gb[d] * W[d * ATTD + a];
    batt[lk * ATTD + a] = s;
}

#define LDSP 40   // LDS row stride in u16 (32 + 8 pad)

// ---------------- MFMA GEMM, BM=64, 4 waves laid out 1x4 across columns ----------------
template<int BN_, int MODE, bool PRESPLIT, bool BIAS, int ACT>
__global__ __launch_bounds__(256) void gemm_mfma(
        const float* __restrict__ A,
        const u16* __restrict__ Ahi, const u16* __restrict__ Alo,
        const u16* __restrict__ Bt, const float* __restrict__ bias,
        float* __restrict__ Cf, u16* __restrict__ Cb,
        int M, int Kd, int Nc) {
    constexpr int JW = BN_ / 64;           // j-frags per wave (wave covers BN_/4 cols)
    __shared__ u16 AsHi[64 * LDSP];
    __shared__ u16 AsLo[64 * LDSP];
    __shared__ u16 Bs[BN_ * LDSP];

    const int tid = threadIdx.x;
    const int lane = tid & 63, wx = tid >> 6;      // wave id 0..3 across columns
    const int lane15 = lane & 15, quad = lane >> 4;
    const int bm = blockIdx.x * 64;
    const int bn = blockIdx.y * BN_;

    floatx4 acc[4][JW];
#pragma unroll
    for (int i = 0; i < 4; ++i)
#pragma unroll
        for (int j = 0; j < JW; ++j) acc[i][j] = (floatx4){0.f, 0.f, 0.f, 0.f};

    for (int k0 = 0; k0 < Kd; k0 += 32) {
        if constexpr (PRESPLIT) {
            {   // 64 rows x 32 u16 per plane = 256 uint4 each; 1 per thread
                int m = tid >> 2, ko = (tid & 3) << 3;
                uint4 vh = make_uint4(0, 0, 0, 0), vl = make_uint4(0, 0, 0, 0);
                if (bm + m < M) {
                    vh = *(const uint4*)(Ahi + (size_t)(bm + m) * Kd + k0 + ko);
                    vl = *(const uint4*)(Alo + (size_t)(bm + m) * Kd + k0 + ko);
                }
                *(uint4*)(void*)(AsHi + m * LDSP + ko) = vh;
                *(uint4*)(void*)(AsLo + m * LDSP + ko) = vl;
            }
        } else {
#pragma unroll
            for (int t = tid; t < 512; t += 256) {
                int m = t >> 3, k4 = (t & 7) << 2;
                float4 v = make_float4(0.f, 0.f, 0.f, 0.f);
                if (bm + m < M) v = *(const float4*)(A + (size_t)(bm + m) * Kd + k0 + k4);
                u16 h0 = f2bf(v.x), h1 = f2bf(v.y), h2 = f2bf(v.z), h3 = f2bf(v.w);
                *(ushort4*)(void*)(AsHi + m * LDSP + k4) = make_ushort4(h0, h1, h2, h3);
                u16 l0 = f2bf(v.x - bf2f(h0)), l1 = f2bf(v.y - bf2f(h1));
                u16 l2 = f2bf(v.z - bf2f(h2)), l3 = f2bf(v.w - bf2f(h3));
                *(ushort4*)(void*)(AsLo + m * LDSP + k4) = make_ushort4(l0, l1, l2, l3);
            }
        }
#pragma unroll
        for (int t = tid; t < BN_ * 4; t += 256) {
            int n = t >> 2, ko = (t & 3) << 3;
            uint4 w = *(const uint4*)(Bt + (size_t)(bn + n) * Kd + k0 + ko);
            *(uint4*)(void*)(Bs + n * LDSP + ko) = w;
        }
        __syncthreads();

        const u16* pA  = AsHi + lane15 * LDSP + quad * 8;
        const u16* pAl = AsLo + lane15 * LDSP + quad * 8;
        const u16* pB  = Bs + (wx * (BN_ / 4) + lane15) * LDSP + quad * 8;
        short8 b[JW];
#pragma unroll
        for (int j = 0; j < JW; ++j) b[j] = *(const short8*)(pB + j * 16 * LDSP);
#pragma unroll
        for (int i = 0; i < 4; ++i) {
            short8 a = *(const short8*)(pA + i * 16 * LDSP);
#pragma unroll
            for (int j = 0; j < JW; ++j)
                acc[i][j] = __builtin_amdgcn_mfma_f32_16x16x32_bf16(a, b[j], acc[i][j], 0, 0, 0);
        }
#pragma unroll
        for (int i = 0; i < 4; ++i) {
            short8 a = *(const short8*)(pAl + i * 16 * LDSP);
#pragma unroll
            for (int j = 0; j < JW; ++j)
                acc[i][j] = __builtin_amdgcn_mfma_f32_16x16x32_bf16(a, b[j], acc[i][j], 0, 0, 0);
        }
        __syncthreads();
    }

#pragma unroll
    for (int i = 0; i < 4; ++i) {
#pragma unroll
        for (int r = 0; r < 4; ++r) {
            int row = bm + i * 16 + quad * 4 + r;
            if (row >= M) continue;
#pragma unroll
            for (int j = 0; j < JW; ++j) {
                int col = bn + wx * (BN_ / 4) + j * 16 + lane15;
                float v = acc[i][j][r];
                if constexpr (BIAS) v += bias[col];
                if constexpr (ACT == 1) v = v > 0.f ? v : SLOPE * v;
                if constexpr (MODE == 0) Cf[(size_t)row * Nc + col] = v;
                else                     Cb[(size_t)row * Nc + col] = f2bf(v);
            }
        }
    }
}

// ---------------- FUSED gather + attention + next-layer GEMM ----------------
// Round-11 structure (BMF=32, 256 thr, B global, 904.7 us base) + phase 5:
// the next layer's GEMM over this block's 32-row h band. h stays in registers
// through phase 4, then lands in the (dead) As LDS as hi/lo planes; phase 5
// computes xw_next[band] = h @ Wnext with Wnext from L2. Deletes 204 MB of
// HBM h-traffic per layer boundary + one GEMM launch. LAST=true (layer 2):
// no phase 5, h written to global for the projection head (round-11 path).
#define BMF 32
#define ALDS 264   // full-row stride in u16 (16B-aligned rows)

template<bool LAST>
__global__ __launch_bounds__(256) void att_fused(
        const int* __restrict__ starts, const int2* __restrict__ edata,
        const u16* __restrict__ xw, const u16* __restrict__ Bt,
        const float* __restrict__ batt, const float* __restrict__ qv,
        const float* __restrict__ gcnb,
        const u16* __restrict__ Wnext, u16* __restrict__ xwout,
        u16* __restrict__ h_hi, u16* __restrict__ h_lo) {
    __shared__ u16 As[KD * BMF * ALDS];          // 33792 B (reused as h hi/lo for phase 5)
    __shared__ float simbuf[KD][2][BMF];         // 512 B

    const int tid = threadIdx.x;
    const int lane = tid & 63, waveid = tid >> 6;
    const int l32 = tid & 31;
    const int hid = tid >> 5;                    // half-wave 0..7
    const int base = lane & 32;                  // shfl base of own half
    const int bm = blockIdx.x * BMF;             // NN % BMF == 0: no tail

    // ---- phase 1: gather 64 node-rows into As, 2 nodes interleaved ----
    {
        const int kk = hid >> 2;                 // halves 0-3: k=0, 4-7: k=1
        const int r0 = (hid & 3) * 8;            // 8 rows per half... (4 rows, 2-node groups)
        const int widx0 = kk * NN + bm + (hid & 3) * 8;
        (void)r0;
        int sv = 0;
        if (l32 < 9) {
            int idx = widx0 - 1 + l32;
            sv = idx >= 0 ? starts[idx] : 0;     // starts[i] = end_i (post csr_fill)
        }
        int2 ed[8];
#pragma unroll
        for (int g = 0; g < 8; ++g) {
            int b = __shfl(sv, base + g), e = __shfl(sv, base + g + 1);
            ed[g] = (l32 < e - b) ? edata[b + l32] : make_int2(0, 0);
        }
#pragma unroll
        for (int g = 0; g < 8; g += 2) {
            int bA = __shfl(sv, base + g),     eA = __shfl(sv, base + g + 1);
            int eB = __shfl(sv, base + g + 2);
            int bB = eA;                          // CSR windows are adjacent
            int dA = eA - bA, dB = eB - bB;
            int mA = dA > 32 ? 32 : dA, mB = dB > 32 ? 32 : dB;
            float4 xa0 = make_float4(0.f,0.f,0.f,0.f), xa1 = make_float4(0.f,0.f,0.f,0.f);
            float4 xb0 = make_float4(0.f,0.f,0.f,0.f), xb1 = make_float4(0.f,0.f,0.f,0.f);
            int j = 0;
            for (; j + 4 <= mA && j + 4 <= mB; j += 4) {
                int ra0 = __shfl(ed[g].x, base + j),     ra1 = __shfl(ed[g].x, base + j + 1);
                int ra2 = __shfl(ed[g].x, base + j + 2), ra3 = __shfl(ed[g].x, base + j + 3);
                int rb0 = __shfl(ed[g+1].x, base + j),     rb1 = __shfl(ed[g+1].x, base + j + 1);
                int rb2 = __shfl(ed[g+1].x, base + j + 2), rb3 = __shfl(ed[g+1].x, base + j + 3);
                float na0 = __int_as_float(__shfl(ed[g].y, base + j));
                float na1 = __int_as_float(__shfl(ed[g].y, base + j + 1));
                float na2 = __int_as_float(__shfl(ed[g].y, base + j + 2));
                float na3 = __int_as_float(__shfl(ed[g].y, base + j + 3));
                float nb0 = __int_as_float(__shfl(ed[g+1].y, base + j));
                float nb1 = __int_as_float(__shfl(ed[g+1].y, base + j + 1));
                float nb2 = __int_as_float(__shfl(ed[g+1].y, base + j + 2));
                float nb3 = __int_as_float(__shfl(ed[g+1].y, base + j + 3));
                uint4 wa0 = *(const uint4*)(xw + (size_t)ra0 * DD + l32 * 8);
                uint4 wa1 = *(const uint4*)(xw + (size_t)ra1 * DD + l32 * 8);
                uint4 wa2 = *(const uint4*)(xw + (size_t)ra2 * DD + l32 * 8);
                uint4 wa3 = *(const uint4*)(xw + (size_t)ra3 * DD + l32 * 8);
                uint4 wb0 = *(const uint4*)(xw + (size_t)rb0 * DD + l32 * 8);
                uint4 wb1 = *(const uint4*)(xw + (size_t)rb1 * DD + l32 * 8);
                uint4 wb2 = *(const uint4*)(xw + (size_t)rb2 * DD + l32 * 8);
                uint4 wb3 = *(const uint4*)(xw + (size_t)rb3 * DD + l32 * 8);
                fma_row8_(xa0, xa1, wa0, na0);
                fma_row8_(xa0, xa1, wa1, na1);
                fma_row8_(xa0, xa1, wa2, na2);
                fma_row8_(xa0, xa1, wa3, na3);
                fma_row8_(xb0, xb1, wb0, nb0);
                fma_row8_(xb0, xb1, wb1, nb1);
                fma_row8_(xb0, xb1, wb2, nb2);
                fma_row8_(xb0, xb1, wb3, nb3);
            }
            int jb = j;
            for (; j + 4 <= mA; j += 4) {
                int ra0 = __shfl(ed[g].x, base + j),     ra1 = __shfl(ed[g].x, base + j + 1);
                int ra2 = __shfl(ed[g].x, base + j + 2), ra3 = __shfl(ed[g].x, base + j + 3);
                float na0 = __int_as_float(__shfl(ed[g].y, base + j));
                float na1 = __int_as_float(__shfl(ed[g].y, base + j + 1));
                float na2 = __int_as_float(__shfl(ed[g].y, base + j + 2));
                float na3 = __int_as_float(__shfl(ed[g].y, base + j + 3));
                uint4 wa0 = *(const uint4*)(xw + (size_t)ra0 * DD + l32 * 8);
                uint4 wa1 = *(const uint4*)(xw + (size_t)ra1 * DD + l32 * 8);
                uint4 wa2 = *(const uint4*)(xw + (size_t)ra2 * DD + l32 * 8);
                uint4 wa3 = *(const uint4*)(xw + (size_t)ra3 * DD + l32 * 8);
                fma_row8_(xa0, xa1, wa0, na0);
                fma_row8_(xa0, xa1, wa1, na1);
                fma_row8_(xa0, xa1, wa2, na2);
                fma_row8_(xa0, xa1, wa3, na3);
            }
            for (; j < mA; ++j) {
                int r = __shfl(ed[g].x, base + j);
                float nv = __int_as_float(__shfl(ed[g].y, base + j));
                uint4 w = *(const uint4*)(xw + (size_t)r * DD + l32 * 8);
                fma_row8_(xa0, xa1, w, nv);
            }
            for (; jb + 4 <= mB; jb += 4) {
                int rb0 = __shfl(ed[g+1].x, base + jb),     rb1 = __shfl(ed[g+1].x, base + jb + 1);
                int rb2 = __shfl(ed[g+1].x, base + jb + 2), rb3 = __shfl(ed[g+1].x, base + jb + 3);
                float nb0 = __int_as_float(__shfl(ed[g+1].y, base + jb));
                float nb1 = __int_as_float(__shfl(ed[g+1].y, base + jb + 1));
                float nb2 = __int_as_float(__shfl(ed[g+1].y, base + jb + 2));
                float nb3 = __int_as_float(__shfl(ed[g+1].y, base + jb + 3));
                uint4 wb0 = *(const uint4*)(xw + (size_t)rb0 * DD + l32 * 8);
                uint4 wb1 = *(const uint4*)(xw + (size_t)rb1 * DD + l32 * 8);
                uint4 wb2 = *(const uint4*)(xw + (size_t)rb2 * DD + l32 * 8);
                uint4 wb3 = *(const uint4*)(xw + (size_t)rb3 * DD + l32 * 8);
                fma_row8_(xb0, xb1, wb0, nb0);
                fma_row8_(xb0, xb1, wb1, nb1);
                fma_row8_(xb0, xb1, wb2, nb2);
                fma_row8_(xb0, xb1, wb3, nb3);
            }
            for (; jb < mB; ++jb) {
                int r = __shfl(ed[g+1].x, base + jb);
                float nv = __int_as_float(__shfl(ed[g+1].y, base + jb));
                uint4 w = *(const uint4*)(xw + (size_t)r * DD + l32 * 8);
                fma_row8_(xb0, xb1, w, nv);
            }
            for (int e2 = bA + 32; e2 < eA; ++e2) {      // rare: degA > 32
                int2 ee = edata[e2];
                float nv = __int_as_float(ee.y);
                uint4 w = *(const uint4*)(xw + (size_t)ee.x * DD + l32 * 8);
                fma_row8_(xa0, xa1, w, nv);
            }
            for (int e2 = bB + 32; e2 < eB; ++e2) {      // rare: degB > 32
                int2 ee = edata[e2];
                float nv = __int_as_float(ee.y);
                uint4 w = *(const uint4*)(xw + (size_t)ee.x * DD + l32 * 8);
                fma_row8_(xb0, xb1, w, nv);
            }
            const int kk2 = hid >> 2;
            const int rr = (hid & 3) * 8;
            u32x4 st;
            st.x = (u32)f2bf(xa0.x) | ((u32)f2bf(xa0.y) << 16);
            st.y = (u32)f2bf(xa0.z) | ((u32)f2bf(xa0.w) << 16);
            st.z = (u32)f2bf(xa1.x) | ((u32)f2bf(xa1.y) << 16);
            st.w = (u32)f2bf(xa1.z) | ((u32)f2bf(xa1.w) << 16);
            *(u32x4*)(void*)(As + (kk2 * BMF + rr + g) * ALDS + l32 * 8) = st;
            st.x = (u32)f2bf(xb0.x) | ((u32)f2bf(xb0.y) << 16);
            st.y = (u32)f2bf(xb0.z) | ((u32)f2bf(xb0.w) << 16);
            st.z = (u32)f2bf(xb1.x) | ((u32)f2bf(xb1.y) << 16);
            st.w = (u32)f2bf(xb1.z) | ((u32)f2bf(xb1.w) << 16);
            *(u32x4*)(void*)(As + (kk2 * BMF + rr + g + 1) * ALDS + l32 * 8) = st;
        }
    }
    __syncthreads();

    // ---- phase 2: MFMA — A from As (read-only), B from global (L2-hot), NO barriers ----
    const int kw = waveid >> 1, ch = waveid & 1;
    const int lane15 = lane & 15, quad = lane >> 4;
    floatx4 acc[2][2];
#pragma unroll
    for (int i = 0; i < 2; ++i)
#pragma unroll
        for (int j = 0; j < 2; ++j) acc[i][j] = (floatx4){0.f, 0.f, 0.f, 0.f};

    const u16* pB0 = Bt + (size_t)kw * ATTD * DD + (size_t)(ch * 32 + lane15) * DD + quad * 8;
    const u16* pB1 = pB0 + 16 * DD;
#pragma unroll
    for (int k0 = 0; k0 < DD; k0 += 32) {
        short8 b0 = *(const short8*)(pB0 + k0);
        short8 b1 = *(const short8*)(pB1 + k0);
        const u16* pA = As + (kw * BMF + lane15) * ALDS + k0 + quad * 8;
#pragma unroll
        for (int i = 0; i < 2; ++i) {
            short8 a = *(const short8*)(pA + i * 16 * ALDS);
            acc[i][0] = __builtin_amdgcn_mfma_f32_16x16x32_bf16(a, b0, acc[i][0], 0, 0, 0);
            acc[i][1] = __builtin_amdgcn_mfma_f32_16x16x32_bf16(a, b1, acc[i][1], 0, 0, 0);
        }
    }

    // ---- phase 3: sim (tanh + q dot, 4-lane-group reduce) ----
#pragma unroll
    for (int i = 0; i < 2; ++i) {
#pragma unroll
        for (int r = 0; r < 4; ++r) {
            float p = 0.f;
#pragma unroll
            for (int j = 0; j < 2; ++j) {
                int col = ch * 32 + j * 16 + lane15;
                float v = acc[i][j][r] + batt[kw * ATTD + col];
                float ex = __expf(2.f * v);
                float th = 1.f - 2.f / (ex + 1.f);     // tanh, inf-safe
                p += th * qv[kw * ATTD + col];
            }
            p += __shfl_xor(p, 1, 64);
            p += __shfl_xor(p, 2, 64);
            p += __shfl_xor(p, 4, 64);
            p += __shfl_xor(p, 8, 64);
            if (lane15 == 0) simbuf[kw][ch][i * 16 + quad * 4 + r] = p;
        }
    }
    __syncthreads();

    // ---- phase 4: combine (softmax over k, relu, hi/lo split) into REGISTERS ----
    // 32 rows x 32 chunks = 1024 items / 256 thr = 4 items each.
    uint4 hw[4], lw[4];
#pragma unroll
    for (int it = 0; it < 4; ++it) {
        int item = tid + it * 256;
        int row = item >> 5, c8 = item & 31;
        float s0 = simbuf[0][0][row] + simbuf[0][1][row];
        float s1 = simbuf[1][0][row] + simbuf[1][1][row];
        float m = fmaxf(s0, s1);
        float e0 = __expf(s0 - m), e1 = __expf(s1 - m);
        float inv = 1.f / (e0 + e1);
        float a0 = e0 * inv, a1 = e1 * inv;
        uint4 x0 = *(const uint4*)(As + row * ALDS + c8 * 8);
        uint4 x1 = *(const uint4*)(As + (BMF + row) * ALDS + c8 * 8);
        const float* bp = gcnb + c8 * 8;
        u16* hp = (u16*)&hw[it]; u16* lp = (u16*)&lw[it];
        const u32* xp0 = (const u32*)&x0; const u32* xp1 = (const u32*)&x1;
#pragma unroll
        for (int j = 0; j < 4; ++j) {
            float2 f0 = __bfloat1622float2(*(const __hip_bfloat162*)&xp0[j]);
            float2 f1 = __bfloat1622float2(*(const __hip_bfloat162*)&xp1[j]);
            float ra = fmaxf(0.f, a0 * f0.x + a1 * f1.x + bp[2 * j]);
            float rb = fmaxf(0.f, a0 * f0.y + a1 * f1.y + bp[2 * j + 1]);
            u16 ha = f2bf(ra), hb = f2bf(rb);
            hp[2 * j] = ha; hp[2 * j + 1] = hb;
            lp[2 * j] = f2bf(ra - bf2f(ha));
            lp[2 * j + 1] = f2bf(rb - bf2f(hb));
        }
    }

    if constexpr (LAST) {
        // final layer: h to global for projection head
#pragma unroll
        for (int it = 0; it < 4; ++it) {
            int item = tid + it * 256;
            int row = item >> 5, c8 = item & 31;
            size_t off = (size_t)(bm + row) * DD + c8 * 8;
            *(uint4*)(h_hi + off) = hw[it];
            *(uint4*)(h_lo + off) = lw[it];
        }
    } else {
        __syncthreads();     // all As (xs) reads done -> safe to overwrite
        // h hi -> As rows 0..31, h lo -> As rows 32..63
#pragma unroll
        for (int it = 0; it < 4; ++it) {
            int item = tid + it * 256;
            int row = item >> 5, c8 = item & 31;
            *(uint4*)(void*)(As + row * ALDS + c8 * 8) = hw[it];
            *(uint4*)(void*)(As + (BMF + row) * ALDS + c8 * 8) = lw[it];
        }
        __syncthreads();

        // ---- phase 5: xw_next[band] = h @ Wnext; Wnext from L2, h from LDS ----
        const int wx = waveid;           // 64 out-cols per wave
        floatx4 acc2[2][4];
#pragma unroll
        for (int i = 0; i < 2; ++i)
#pragma unroll
            for (int j = 0; j < 4; ++j) acc2[i][j] = (floatx4){0.f, 0.f, 0.f, 0.f};

#pragma unroll
        for (int k0 = 0; k0 < DD; k0 += 32) {
            short8 b[4];
#pragma unroll
            for (int j = 0; j < 4; ++j)
                b[j] = *(const short8*)(Wnext + (size_t)(wx * 64 + j * 16 + lane15) * DD + k0 + quad * 8);
#pragma unroll
            for (int i = 0; i < 2; ++i) {
                short8 ahi = *(const short8*)(As + (i * 16 + lane15) * ALDS + k0 + quad * 8);
                short8 alo = *(const short8*)(As + (BMF + i * 16 + lane15) * ALDS + k0 + quad * 8);
#pragma unroll
                for (int j = 0; j < 4; ++j) {
                    acc2[i][j] = __builtin_amdgcn_mfma_f32_16x16x32_bf16(ahi, b[j], acc2[i][j], 0, 0, 0);
                    acc2[i][j] = __builtin_amdgcn_mfma_f32_16x16x32_bf16(alo, b[j], acc2[i][j], 0, 0, 0);
                }
            }
        }
#pragma unroll
        for (int i = 0; i < 2; ++i)
#pragma unroll
            for (int r = 0; r < 4; ++r) {
                int row = bm + i * 16 + quad * 4 + r;
#pragma unroll
                for (int j = 0; j < 4; ++j) {
                    int col = wx * 64 + j * 16 + lane15;
                    xwout[(size_t)row * DD + col] = f2bf(acc2[i][j][r]);
                }
            }
    }
}

extern "C" void kernel_launch(void* const* d_in, const int* in_sizes, int n_in,
                              void* d_out, int out_size, void* d_ws, size_t ws_size,
                              hipStream_t stream) {
    const float* x     = (const float*)d_in[0];
    const int*   ei    = (const int*)d_in[1];
    const float* ew    = (const float*)d_in[2];
    const float* gamma = (const float*)d_in[3];
    const float* beta  = (const float*)d_in[4];
    const float* gcn_W = (const float*)d_in[5];
    const float* gcn_b = (const float*)d_in[6];
    const float* att_W = (const float*)d_in[7];
    const float* att_b = (const float*)d_in[8];
    const float* att_q = (const float*)d_in[9];
    const float* pW1   = (const float*)d_in[10];
    const float* pb1   = (const float*)d_in[11];
    const float* pW2   = (const float*)d_in[12];
    const float* pb2   = (const float*)d_in[13];
    float* out = (float*)d_out;

    char* wsb = (char*)d_ws;
    size_t off = 0;
    auto alloc = [&](size_t bytes) -> void* {
        void* p = wsb + off;
        off += (bytes + 255) & ~(size_t)255;
        return p;
    };
    u16*   h_hi  = (u16*)alloc((size_t)NN * DD * 2);          // 51.2 MB
    u16*   h_lo  = (u16*)alloc((size_t)NN * DD * 2);          // 51.2 MB
    u16*   xw_a  = (u16*)alloc((size_t)NN * DD * 2);          // 51.2 MB
    u16*   xw_b  = (u16*)alloc((size_t)NN * DD * 2);          // 51.2 MB
    float* p1tmp = (float*)xw_b;                              // free after fused l=1... reused by proj (xw_b dead then)
    float* dinv  = (float*)alloc((size_t)KN * 4);
    int*   starts= (int*)alloc(((size_t)KN + 1) * 4);
    u64*   dc    = (u64*)alloc((size_t)KN * 8);               // packed deg+count
    int2*  edata = (int2*)alloc((size_t)KD * EE * 8);         // 6.4 MB
    float* bnsums= (float*)alloc(2 * DD * 4);
    u16*   gcnWb = (u16*)alloc((size_t)LL * DD * DD * 2);
    u16*   attWb = (u16*)alloc((size_t)LL * KD * ATTD * DD * 2);
    u16*   pW1b  = (u16*)alloc((size_t)HH1 * DD * 2);
    u16*   pW2b  = (u16*)alloc((size_t)HH2 * HH1 * 2);
    float* batt  = (float*)alloc((size_t)LL * KD * ATTD * 4);
    int*   bsums = (int*)alloc((size_t)SCAN_NB * 4);

    // ---- setup: all weight converts in ONE kernel + att bias fold ----
    wconv_all<<<(WC_TOTAL + 255) / 256, 256, 0, stream>>>(
        gcn_W, gcnWb, att_W, attWb, pW1, pW1b, pW2, pW2b);
    att_bias_fold<<<LL * KD, ATTD, 0, stream>>>(att_W, att_b, gcn_b, batt);

    // ---- BatchNorm -> h (pre-split) ----
    hipMemsetAsync(bnsums, 0, 2 * DD * 4, stream);
    bn_stats<<<800, 256, 0, stream>>>(x, bnsums);
    bn_apply<<<25000, 256, 0, stream>>>(x, bnsums, gamma, beta, h_hi, h_lo);

    // ---- degree / CSR (layer-invariant); single packed-atomic pass ----
    hipMemsetAsync(dc, 0, (size_t)KN * 8, stream);
    deg_count<<<(KD * EE + 255) / 256, 256, 0, stream>>>(ei, ew, dc);
    dinv_pack<<<(KN + 255) / 256, 256, 0, stream>>>(dc, dinv, starts);
    scan_blocks<<<SCAN_NB, 256, 0, stream>>>(starts, bsums);
    scan_sums<<<1, 1024, 0, stream>>>(bsums);
    scan_add<<<SCAN_NB, 256, 0, stream>>>(starts, bsums);
    csr_fill<<<(KD * EE + 255) / 256, 256, 0, stream>>>(ei, ew, dinv, starts, edata);

    const int MB64 = (NN + 63) / 64;     // 1563
    const int MBF  = NN / BMF;           // 3125 exact

    // layer 0 GEMM (from bn h), then fused chain: xw_a -> xw_b -> xw_a -> h
    gemm_mfma<256, 1, true, false, 0><<<dim3(MB64, 1), 256, 0, stream>>>(
        nullptr, h_hi, h_lo, gcnWb, nullptr, nullptr, xw_a, NN, DD, DD);

    att_fused<false><<<MBF, 256, 0, stream>>>(
        starts, edata, xw_a, attWb + (size_t)0 * KD * ATTD * DD,
        batt + 0 * KD * ATTD, att_q + 0 * KD * ATTD, gcn_b + 0 * DD,
        gcnWb + (size_t)1 * DD * DD, xw_b, nullptr, nullptr);

    att_fused<false><<<MBF, 256, 0, stream>>>(
        starts, edata, xw_b, attWb + (size_t)1 * KD * ATTD * DD,
        batt + 1 * KD * ATTD, att_q + 1 * KD * ATTD, gcn_b + 1 * DD,
        gcnWb + (size_t)2 * DD * DD, xw_a, nullptr, nullptr);

    att_fused<true><<<MBF, 256, 0, stream>>>(
        starts, edata, xw_a, attWb + (size_t)2 * KD * ATTD * DD,
        batt + 2 * KD * ATTD, att_q + 2 * KD * ATTD, gcn_b + 2 * DD,
        nullptr, nullptr, h_hi, h_lo);

    // ---- projection head ----
    gemm_mfma<128, 0, true, true, 1><<<dim3(MB64, 1), 256, 0, stream>>>(
        nullptr, h_hi, h_lo, pW1b, pb1, p1tmp, nullptr, NN, DD, HH1);
    gemm_mfma<64, 0, false, true, 1><<<dim3(MB64, 1), 256, 0, stream>>>(
        p1tmp, nullptr, nullptr, pW2b, pb2, out, nullptr, NN, HH1, HH2);
}